// Round 1
// baseline (390.436 us; speedup 1.0000x reference)
//
#include <hip/hip_runtime.h>

typedef unsigned long long u64;

// ---------- sortable key packing ----------
// ord32: monotone float -> uint32 (handles negatives); unique per distinct float
__device__ __forceinline__ unsigned ord32(float f) {
  unsigned u = __float_as_uint(f);
  return (u & 0x80000000u) ? ~u : (u | 0x80000000u);
}
// max-key: descending score, ties -> ascending index (matches jax.lax.top_k)
__device__ __forceinline__ u64 packMax(float f, int n) {
  return ((u64)ord32(f) << 32) | (unsigned)(~(unsigned)n);
}
// min-key = max-key ^ 0xFFFFFFFF : ascending score, ties -> ascending index

// ---------- 64-lane wave reductions on u64 ----------
__device__ __forceinline__ u64 shfl_xor64(u64 x, int m) {
  unsigned lo = (unsigned)x, hi = (unsigned)(x >> 32);
  lo = (unsigned)__shfl_xor((int)lo, m, 64);
  hi = (unsigned)__shfl_xor((int)hi, m, 64);
  return ((u64)hi << 32) | lo;
}
__device__ __forceinline__ u64 wave_max64(u64 x) {
#pragma unroll
  for (int m = 32; m; m >>= 1) { u64 y = shfl_xor64(x, m); if (y > x) x = y; }
  return x;
}
__device__ __forceinline__ u64 wave_min64(u64 x) {
#pragma unroll
  for (int m = 32; m; m >>= 1) { u64 y = shfl_xor64(x, m); if (y < x) x = y; }
  return x;
}

#define SB 256   // items per block
#define BT 32    // basket tile per block

// scores[b][n] = sum_d v[d] * tanh(bproj[b][d] + iproj[n][d])
__global__ void __launch_bounds__(256)
scores_kernel(const float* __restrict__ basket, const float* __restrict__ item,
              const float* __restrict__ Wb, const float* __restrict__ Wi,
              const float* __restrict__ v, float* __restrict__ scores,
              int N, int B) {
  __shared__ float WL[64 * 64];   // Wb then Wi
  __shared__ float bp[BT * 64];   // basket projections for this tile
  __shared__ float vs[64];

  int tid = threadIdx.x;
  int b0 = blockIdx.y * BT;

  for (int i = tid; i < 4096; i += 256) WL[i] = Wb[i];
  if (tid < 64) vs[tid] = v[tid];
  __syncthreads();

  // basket projection tile: thread t -> basket (t & 31), d in [(t>>5)*8, +8)
  {
    int b_l = tid & 31;
    int dbase = (tid >> 5) * 8;
    int bg = b0 + b_l;
    if (bg < B) {
      for (int j = 0; j < 8; ++j) {
        int d = dbase + j;
        float acc = 0.f;
#pragma unroll
        for (int e = 0; e < 64; ++e)
          acc = fmaf(basket[bg * 64 + e], WL[d * 64 + e], acc);  // WL read is wave-uniform -> broadcast
        bp[b_l * 64 + d] = acc;
      }
    } else {
      for (int j = 0; j < 8; ++j) bp[b_l * 64 + dbase + j] = 0.f;
    }
  }
  __syncthreads();
  for (int i = tid; i < 4096; i += 256) WL[i] = Wi[i];
  __syncthreads();

  int n = blockIdx.x * SB + tid;
  bool active = (n < N);

  float row[64];
  if (active) {
    const float4* p = (const float4*)(item + (size_t)n * 64);
#pragma unroll
    for (int i = 0; i < 16; ++i) {
      float4 t = p[i];
      row[4 * i + 0] = t.x; row[4 * i + 1] = t.y;
      row[4 * i + 2] = t.z; row[4 * i + 3] = t.w;
    }
  }

  // item projection in registers (fully unrolled: static indexing, no scratch)
  float ip[64];
  if (active) {
#pragma unroll
    for (int d = 0; d < 64; ++d) {
      float acc = 0.f;
#pragma unroll
      for (int e = 0; e < 64; ++e)
        acc = fmaf(row[e], WL[d * 64 + e], acc);
      ip[d] = acc;
    }
  }

  if (!active) return;  // no barriers below

  int nBas = (B - b0 < BT) ? (B - b0) : BT;
  for (int b = 0; b < nBas; ++b) {
    double acc = 0.0;
#pragma unroll
    for (int d = 0; d < 64; ++d) {
      float x = bp[b * 64 + d] + ip[d];
      // tanh(x) = 1 - 2/(exp(2x)+1); exp2-based, ~1ulp
      float u = __builtin_amdgcn_exp2f(x * 2.8853900817779268f); // 2*log2(e)
      float rr = __builtin_amdgcn_rcpf(u + 1.0f);
      double td = fma(-2.0, (double)rr, 1.0);   // tanh in double (exact from f32 r)
      acc = fma((double)vs[d], td, acc);        // f64 accumulation for ranking stability
    }
    scores[(size_t)(b0 + b) * N + n] = (float)acc;
  }
}

// exact top-K (pos) and bottom-K (neg) per row, jax.lax.top_k tie semantics
__global__ void __launch_bounds__(1024)
select_kernel(const float* __restrict__ scores, int* __restrict__ out,
              int N, int B, int K) {
  int b = blockIdx.x;
  const float* row = scores + (size_t)b * N;
  int tid = threadIdx.x;
  int lane = tid & 63, wid = tid >> 6;
  __shared__ u64 wmax[16], wmin[16];

  // initial scan: per-thread best candidates (sentinels: 0 for max, ~0 for min;
  // real keys always have ord>=0x00800000 so sentinels never win)
  u64 lbMax = 0ull, lbMin = ~0ull;
  for (int n = tid; n < N; n += 1024) {
    u64 kk = packMax(row[n], n);
    if (kk > lbMax) lbMax = kk;
    u64 km = kk ^ 0xFFFFFFFFull;
    if (km < lbMin) lbMin = km;
  }
  {
    u64 wm = wave_max64(lbMax);
    u64 wn = wave_min64(lbMin);
    if (lane == 0) { wmax[wid] = wm; wmin[wid] = wn; }
  }
  __syncthreads();

  int* pos = out + (size_t)b * K;
  int* neg = out + (size_t)B * K + (size_t)b * K;

  for (int r = 0; r < K; ++r) {
    u64 gmax = 0ull, gmin = ~0ull;
#pragma unroll
    for (int i = 0; i < 16; ++i) {
      u64 a = wmax[i]; if (a > gmax) gmax = a;
      u64 c = wmin[i]; if (c < gmin) gmin = c;
    }
    bool iwinMax = (lbMax == gmax);  // exactly one thread (keys unique)
    bool iwinMin = (lbMin == gmin);
    u64 mmax = __ballot(iwinMax);
    u64 mmin = __ballot(iwinMin);
    __syncthreads();  // all wmax/wmin reads done before rewrites

    if (mmax) {  // wave-uniform: this wave holds the max-winner
      if (iwinMax) pos[r] = (int)(~(unsigned)gmax);
      int wl = __ffsll(mmax) - 1;
      int wtid = (wid << 6) + wl;
      int nn = wtid + lane * 1024;   // winner's elements, one per lane
      u64 kk = 0ull;
      if (nn < N) {
        u64 t = packMax(row[nn], nn);
        if (t < gmax) kk = t;        // strictly below new bound
      }
      u64 nb = wave_max64(kk);
      if (iwinMax) lbMax = nb;
      u64 wm2 = wave_max64(lbMax);
      if (lane == 0) wmax[wid] = wm2;
    }
    if (mmin) {
      if (iwinMin) neg[r] = (int)(unsigned)gmin;
      int wl = __ffsll(mmin) - 1;
      int wtid = (wid << 6) + wl;
      int nn = wtid + lane * 1024;
      u64 kk = ~0ull;
      if (nn < N) {
        u64 t = packMax(row[nn], nn) ^ 0xFFFFFFFFull;
        if (t > gmin) kk = t;        // strictly above new bound
      }
      u64 nb = wave_min64(kk);
      if (iwinMin) lbMin = nb;
      u64 wn2 = wave_min64(lbMin);
      if (lane == 0) wmin[wid] = wn2;
    }
    __syncthreads();  // updated wave bests visible before next round's reads
  }
}

extern "C" void kernel_launch(void* const* d_in, const int* in_sizes, int n_in,
                              void* d_out, int out_size, void* d_ws, size_t ws_size,
                              hipStream_t stream) {
  const float* basket = (const float*)d_in[0];
  const float* item   = (const float*)d_in[1];
  const float* Wb     = (const float*)d_in[2];
  const float* Wi     = (const float*)d_in[3];
  const float* v      = (const float*)d_in[4];
  // d_in[5] is k; derive K host-side from out_size instead (no device read needed)
  int D = in_sizes[4];           // 64
  int B = in_sizes[0] / D;       // 128
  int N = in_sizes[1] / D;       // 50000
  int K = out_size / (2 * B);    // 50

  float* scores = (float*)d_ws;  // B*N floats = 25.6 MB

  dim3 gs((N + SB - 1) / SB, (B + BT - 1) / BT);
  scores_kernel<<<gs, dim3(256), 0, stream>>>(basket, item, Wb, Wi, v, scores, N, B);
  select_kernel<<<dim3(B), dim3(1024), 0, stream>>>(scores, (int*)d_out, N, B, K);
}

// Round 2
// 229.768 us; speedup vs baseline: 1.6993x; 1.6993x over previous
//
#include <hip/hip_runtime.h>

typedef unsigned long long u64;

#define CSC 2.8853900817779268f   // 2*log2(e): tanh(x) = 1 - 2/(exp2(x*CSC)+1)

// ---------- sortable key packing ----------
__device__ __forceinline__ unsigned ord32(float f) {
  unsigned u = __float_as_uint(f);
  return (u & 0x80000000u) ? ~u : (u | 0x80000000u);
}
// max-key: descending score, ties -> ascending index (matches jax.lax.top_k)
__device__ __forceinline__ u64 packMax(float f, int n) {
  return ((u64)ord32(f) << 32) | (unsigned)(~(unsigned)n);
}
// min-key = max-key ^ 0xFFFFFFFF : ascending score, ties -> ascending index

// ================= prep: projections, prescaled by CSC =================
// ipT [64][N] (transposed for coalesced access), bpS [B][64]
__global__ void __launch_bounds__(256)
prep_kernel(const float* __restrict__ basket, const float* __restrict__ item,
            const float* __restrict__ Wb, const float* __restrict__ Wi,
            float* __restrict__ ipT, float* __restrict__ bpS, int N, int B) {
  __shared__ float WL[4096];
  int tid = threadIdx.x;

  if (blockIdx.x == gridDim.x - 1) {           // basket block
    for (int i = tid; i < 4096; i += 256) WL[i] = Wb[i];
    __syncthreads();
    for (int idx = tid; idx < B * 64; idx += 256) {
      int b = idx >> 6, d = idx & 63;
      float acc = 0.f;
#pragma unroll
      for (int e = 0; e < 64; ++e) acc = fmaf(basket[b * 64 + e], WL[d * 64 + e], acc);
      bpS[idx] = acc * CSC;
    }
    return;
  }

  for (int i = tid; i < 4096; i += 256) WL[i] = Wi[i];
  __syncthreads();
  int n = blockIdx.x * 256 + tid;
  if (n >= N) return;

  float row[64];
  const float4* p = (const float4*)(item + (size_t)n * 64);
#pragma unroll
  for (int i = 0; i < 16; ++i) {
    float4 t = p[i];
    row[4 * i] = t.x; row[4 * i + 1] = t.y; row[4 * i + 2] = t.z; row[4 * i + 3] = t.w;
  }
#pragma unroll
  for (int d = 0; d < 64; ++d) {
    float acc = 0.f;
#pragma unroll
    for (int e = 0; e < 64; ++e) acc = fmaf(row[e], WL[d * 64 + e], acc);
    ipT[(size_t)d * N + n] = acc * CSC;       // coalesced store
  }
}

// ================= scores =================
#define BT 16
__global__ void __launch_bounds__(256)
scores_kernel(const float* __restrict__ ipT, const float* __restrict__ bpS,
              const float* __restrict__ v, float* __restrict__ scores, int N, int B) {
  __shared__ float bp[BT * 64];
  __shared__ float vs[64];
  int tid = threadIdx.x;
  int b0 = blockIdx.y * BT;

  for (int i = tid; i < BT * 64; i += 256) bp[i] = bpS[b0 * 64 + i];
  if (tid < 64) vs[tid] = v[tid];
  __syncthreads();

  int n = blockIdx.x * 256 + tid;
  if (n >= N) return;

  float ip[64];
#pragma unroll
  for (int d = 0; d < 64; ++d) ip[d] = ipT[(size_t)d * N + n];  // coalesced

  double sv = 0.0;
#pragma unroll
  for (int d = 0; d < 64; ++d) sv += (double)vs[d];

  int nb = (B - b0 < BT) ? (B - b0) : BT;
  for (int b = 0; b < nb; ++b) {
    double acc = 0.0;
#pragma unroll
    for (int g = 0; g < 8; ++g) {
      float gs = 0.f;
#pragma unroll
      for (int j = 0; j < 8; ++j) {
        int d = g * 8 + j;
        float x = bp[b * 64 + d] + ip[d];      // both prescaled by CSC
        float u = __builtin_amdgcn_exp2f(x);
        float r = __builtin_amdgcn_rcpf(u + 1.0f);
        gs = fmaf(vs[d], r, gs);               // f32 group accumulation
      }
      acc += (double)gs;                       // f64 fold every 8 terms
    }
    // score = sum_d v_d*(1-2r_d) = sum(v) - 2*sum(v_d*r_d)
    scores[(size_t)(b0 + b) * N + n] = (float)(sv - 2.0 * acc);
  }
}

// ================= exact top-K / bottom-K via histogram select =================
#define NBIN 4096
#define CAP  2048
__global__ void __launch_bounds__(512)
select_kernel(const float* __restrict__ scores, const float* __restrict__ v,
              int* __restrict__ out, int N, int B, int K) {
  __shared__ int hist[NBIN];
  __shared__ int part[64];
  __shared__ u64 candP[CAP], candN[CAP];
  __shared__ int cntP, cntN, hHi, hLo;
  __shared__ float vsh[64];
  int tid = threadIdx.x;
  int b = blockIdx.x;
  const float* row = scores + (size_t)b * N;

  if (tid < 64) vsh[tid] = v[tid];
  for (int i = tid; i < NBIN; i += 512) hist[i] = 0;
  if (tid == 0) { cntP = 0; cntN = 0; }
  __syncthreads();

  // |score| < R = sum|v_d| strictly (|tanh|<1) -> linear bins over [-R, R]
  float R = 0.f;
#pragma unroll
  for (int d = 0; d < 64; ++d) R += fabsf(vsh[d]);   // identical in all threads
  float invW = (float)NBIN / (2.0f * R);

  // pass 1: histogram
  for (int n = tid; n < N; n += 512) {
    float s = row[n];
    int bi = (int)((s + R) * invW);
    bi = bi < 0 ? 0 : (bi > NBIN - 1 ? NBIN - 1 : bi);
    atomicAdd(&hist[bi], 1);
  }
  __syncthreads();

  if (tid < 64) {                 // 64-bin chunk sums (wave 0, parallel)
    int ssum = 0;
    for (int j = 0; j < 64; ++j) ssum += hist[tid * 64 + j];
    part[tid] = ssum;
  }
  __syncthreads();

  if (tid == 0) {                 // top threshold bin (wave 0)
    int cum = 0, c = 63;
    for (; c > 0; --c) { if (cum + part[c] >= K) break; cum += part[c]; }
    int h = c * 64 + 63;
    for (;; --h) { cum += hist[h]; if (cum >= K || h == 0) break; }
    hHi = h;
  }
  if (tid == 64) {                // bottom threshold bin (wave 1, concurrent)
    int cum = 0, c = 0;
    for (; c < 63; ++c) { if (cum + part[c] >= K) break; cum += part[c]; }
    int h = c * 64;
    for (;; ++h) { cum += hist[h]; if (cum >= K || h == NBIN - 1) break; }
    hLo = h;
  }
  __syncthreads();
  int hi = hHi, lo = hLo;

  // pass 2: compact candidates (cnt in [K, K+binCount-1], expected ~K+2)
  for (int n = tid; n < N; n += 512) {
    float s = row[n];
    int bi = (int)((s + R) * invW);
    bi = bi < 0 ? 0 : (bi > NBIN - 1 ? NBIN - 1 : bi);
    if (bi >= hi) { int i = atomicAdd(&cntP, 1); if (i < CAP) candP[i] = packMax(s, n); }
    if (bi <= lo) { int i = atomicAdd(&cntN, 1); if (i < CAP) candN[i] = packMax(s, n) ^ 0xFFFFFFFFull; }
  }
  __syncthreads();

  int tP = cntP < CAP ? cntP : CAP;
  int tN = cntN < CAP ? cntN : CAP;
  int* pos = out + (size_t)b * K;
  int* neg = out + (size_t)B * K + (size_t)b * K;

  // exact ranking, O(C^2); keys unique -> ranks unique & complete
  for (int i = tid; i < tP; i += 512) {
    u64 key = candP[i]; int r = 0;
    for (int j = 0; j < tP; ++j) r += (candP[j] > key);
    if (r < K) pos[r] = (int)(~(unsigned)key);
  }
  for (int i = tid; i < tN; i += 512) {
    u64 key = candN[i]; int r = 0;
    for (int j = 0; j < tN; ++j) r += (candN[j] < key);
    if (r < K) neg[r] = (int)(unsigned)key;
  }
}

extern "C" void kernel_launch(void* const* d_in, const int* in_sizes, int n_in,
                              void* d_out, int out_size, void* d_ws, size_t ws_size,
                              hipStream_t stream) {
  const float* basket = (const float*)d_in[0];
  const float* item   = (const float*)d_in[1];
  const float* Wb     = (const float*)d_in[2];
  const float* Wi     = (const float*)d_in[3];
  const float* v      = (const float*)d_in[4];
  int D = in_sizes[4];           // 64
  int B = in_sizes[0] / D;       // 128
  int N = in_sizes[1] / D;       // 50000
  int K = out_size / (2 * B);    // 50

  float* scores = (float*)d_ws;                         // B*N  = 25.6 MB
  float* ipT    = scores + (size_t)B * N;               // 64*N = 12.8 MB
  float* bpS    = ipT + (size_t)64 * N;                 // B*64 = 32 KB

  int nItemBlk = (N + 255) / 256;
  prep_kernel<<<dim3(nItemBlk + 1), dim3(256), 0, stream>>>(basket, item, Wb, Wi, ipT, bpS, N, B);

  dim3 gs(nItemBlk, (B + BT - 1) / BT);
  scores_kernel<<<gs, dim3(256), 0, stream>>>(ipT, bpS, v, scores, N, B);

  select_kernel<<<dim3(B), dim3(512), 0, stream>>>(scores, v, (int*)d_out, N, B, K);
}

// Round 3
// 149.154 us; speedup vs baseline: 2.6177x; 1.5405x over previous
//
#include <hip/hip_runtime.h>

typedef unsigned long long u64;

#define CSC 2.8853900817779268f   // 2*log2(e): tanh(x) = 1 - 2/(exp2(x*CSC)+1)
#define NBIN 4096
#define CAP  256
#define BT   16
#define PB   128

// ---------- sortable key packing ----------
__device__ __forceinline__ unsigned ord32(float f) {
  unsigned u = __float_as_uint(f);
  return (u & 0x80000000u) ? ~u : (u | 0x80000000u);
}
// max-key: descending score, ties -> ascending index (jax.lax.top_k semantics)
__device__ __forceinline__ u64 packMax(float f, int n) {
  return ((u64)ord32(f) << 32) | (unsigned)(~(unsigned)n);
}

// ================= prep: E = exp2(CSC * proj) =================
// ipE [N][64] (row-major, float4-friendly), bpE [B][64]
__global__ void __launch_bounds__(128)
prep_kernel(const float* __restrict__ basket, const float* __restrict__ item,
            const float* __restrict__ Wb, const float* __restrict__ Wi,
            float* __restrict__ ipE, float* __restrict__ bpE,
            int N, int B, int nItemBlk) {
  __shared__ float WL[4096];
  int tid = threadIdx.x;

  if (blockIdx.x >= nItemBlk) {                // 4 basket blocks
    for (int i = tid; i < 4096; i += PB) WL[i] = Wb[i];
    __syncthreads();
    int which = blockIdx.x - nItemBlk;
    int seg = (B * 64 + 3) / 4;
    int lo = which * seg, hi = min(lo + seg, B * 64);
    for (int idx = lo + tid; idx < hi; idx += PB) {
      int b = idx >> 6, d = idx & 63;
      float acc = 0.f;
#pragma unroll
      for (int e = 0; e < 64; ++e) acc = fmaf(basket[b * 64 + e], WL[d * 64 + e], acc);
      bpE[idx] = __builtin_amdgcn_exp2f(acc * CSC);
    }
    return;
  }

  for (int i = tid; i < 4096; i += PB) WL[i] = Wi[i];
  __syncthreads();
  int n = blockIdx.x * PB + tid;
  if (n >= N) return;

  float row[64];
  const float4* p = (const float4*)(item + (size_t)n * 64);
#pragma unroll
  for (int i = 0; i < 16; ++i) {
    float4 t = p[i];
    row[4 * i] = t.x; row[4 * i + 1] = t.y; row[4 * i + 2] = t.z; row[4 * i + 3] = t.w;
  }
  float4* op = (float4*)(ipE + (size_t)n * 64);
#pragma unroll
  for (int q = 0; q < 16; ++q) {
    float4 o;
    float a0 = 0.f, a1 = 0.f, a2 = 0.f, a3 = 0.f;
#pragma unroll
    for (int e = 0; e < 64; ++e) {
      float re = row[e];
      a0 = fmaf(re, WL[(4 * q + 0) * 64 + e], a0);
      a1 = fmaf(re, WL[(4 * q + 1) * 64 + e], a1);
      a2 = fmaf(re, WL[(4 * q + 2) * 64 + e], a2);
      a3 = fmaf(re, WL[(4 * q + 3) * 64 + e], a3);
    }
    o.x = __builtin_amdgcn_exp2f(a0 * CSC);
    o.y = __builtin_amdgcn_exp2f(a1 * CSC);
    o.z = __builtin_amdgcn_exp2f(a2 * CSC);
    o.w = __builtin_amdgcn_exp2f(a3 * CSC);
    op[q] = o;
  }
}

// ================= scores: 3 VALU ops / term =================
__global__ void __launch_bounds__(256)
scores_kernel(const float* __restrict__ ipE, const float* __restrict__ bpE,
              const float* __restrict__ v, float* __restrict__ scores, int N, int B) {
  int tid = threadIdx.x;
  int b0 = blockIdx.y * BT;
  int n = blockIdx.x * 256 + tid;
  if (n >= N) return;

  float ei[64];
  const float4* p = (const float4*)(ipE + (size_t)n * 64);
#pragma unroll
  for (int i = 0; i < 16; ++i) {
    float4 t = p[i];
    ei[4 * i] = t.x; ei[4 * i + 1] = t.y; ei[4 * i + 2] = t.z; ei[4 * i + 3] = t.w;
  }

  double sv = 0.0;
#pragma unroll
  for (int d = 0; d < 64; ++d) sv += (double)v[d];   // uniform -> s_load + hoist

  int nb = (B - b0 < BT) ? (B - b0) : BT;
  for (int b = 0; b < nb; ++b) {
    const float* eb = bpE + (size_t)(b0 + b) * 64;   // uniform -> s_load
    double acc = 0.0;
#pragma unroll
    for (int g = 0; g < 8; ++g) {
      float gs = 0.f;
#pragma unroll
      for (int j = 0; j < 8; ++j) {
        int d = g * 8 + j;
        float u1 = fmaf(eb[d], ei[d], 1.0f);         // exp2(b+i)+1 via product
        float r  = __builtin_amdgcn_rcpf(u1);
        gs = fmaf(v[d], r, gs);
      }
      acc += (double)gs;                             // f64 fold every 8 terms
    }
    scores[(size_t)(b0 + b) * N + n] = (float)(sv - 2.0 * acc);
  }
}

// ================= select stage A: per-chunk histogram =================
__global__ void __launch_bounds__(256)
hist_kernel(const float* __restrict__ scores, const float* __restrict__ v,
            int* __restrict__ hist, int N, int CH) {
  __shared__ int lh[NBIN];
  int tid = threadIdx.x, b = blockIdx.y;
  for (int i = tid; i < NBIN; i += 256) lh[i] = 0;
  float R = 0.f;
#pragma unroll
  for (int d = 0; d < 64; ++d) R += fabsf(v[d]);     // uniform
  float invW = (float)NBIN / (2.f * R);
  __syncthreads();

  const float* row = scores + (size_t)b * N;
  int start = blockIdx.x * CH;
  for (int k = 0; k * 1024 < CH; ++k) {
    int n = start + k * 1024 + tid * 4;
    if (n + 3 < N) {
      float4 s4 = *(const float4*)(row + n);
      int b0i = (int)((s4.x + R) * invW); b0i = b0i < 0 ? 0 : (b0i > NBIN - 1 ? NBIN - 1 : b0i);
      int b1i = (int)((s4.y + R) * invW); b1i = b1i < 0 ? 0 : (b1i > NBIN - 1 ? NBIN - 1 : b1i);
      int b2i = (int)((s4.z + R) * invW); b2i = b2i < 0 ? 0 : (b2i > NBIN - 1 ? NBIN - 1 : b2i);
      int b3i = (int)((s4.w + R) * invW); b3i = b3i < 0 ? 0 : (b3i > NBIN - 1 ? NBIN - 1 : b3i);
      atomicAdd(&lh[b0i], 1); atomicAdd(&lh[b1i], 1);
      atomicAdd(&lh[b2i], 1); atomicAdd(&lh[b3i], 1);
    } else {
      for (int j = 0; j < 4; ++j) {
        if (n + j < N) {
          float s = row[n + j];
          int bi = (int)((s + R) * invW); bi = bi < 0 ? 0 : (bi > NBIN - 1 ? NBIN - 1 : bi);
          atomicAdd(&lh[bi], 1);
        }
      }
    }
  }
  __syncthreads();
  for (int i = tid; i < NBIN; i += 256)
    if (lh[i]) atomicAdd(&hist[(size_t)b * NBIN + i], lh[i]);
}

// ================= select stage B: per-row thresholds =================
__global__ void __launch_bounds__(64)
thr_kernel(const int* __restrict__ hist, int* __restrict__ thr, int K) {
  __shared__ int lh[NBIN];
  __shared__ int part[64];
  int t = threadIdx.x, b = blockIdx.x;
  const int* h = hist + (size_t)b * NBIN;
  for (int i = t; i < NBIN; i += 64) lh[i] = h[i];   // coalesced stage
  __syncthreads();
  int s = 0;
  for (int j = 0; j < 64; ++j) s += lh[t * 64 + j];
  part[t] = s;
  __syncthreads();
  if (t == 0) {
    int cum = 0, c = 63;
    for (; c > 0; --c) { if (cum + part[c] >= K) break; cum += part[c]; }
    int hh = c * 64 + 63;
    for (;; --hh) { cum += lh[hh]; if (cum >= K || hh == 0) break; }
    thr[2 * b] = hh;
  }
  if (t == 1) {
    int cum = 0, c = 0;
    for (; c < 63; ++c) { if (cum + part[c] >= K) break; cum += part[c]; }
    int hl = c * 64;
    for (;; ++hl) { cum += lh[hl]; if (cum >= K || hl == NBIN - 1) break; }
    thr[2 * b + 1] = hl;
  }
}

// ================= select stage C: compact candidates =================
__global__ void __launch_bounds__(256)
compact_kernel(const float* __restrict__ scores, const float* __restrict__ v,
               const int* __restrict__ thr, int* __restrict__ cnt,
               u64* __restrict__ candP, u64* __restrict__ candN, int N, int CH) {
  int tid = threadIdx.x, b = blockIdx.y;
  float R = 0.f;
#pragma unroll
  for (int d = 0; d < 64; ++d) R += fabsf(v[d]);
  float invW = (float)NBIN / (2.f * R);
  int hi = thr[2 * b], lo = thr[2 * b + 1];
  const float* row = scores + (size_t)b * N;
  u64* cp = candP + (size_t)b * CAP;
  u64* cn = candN + (size_t)b * CAP;
  int start = blockIdx.x * CH;
  for (int k = 0; k * 1024 < CH; ++k) {
    int n = start + k * 1024 + tid * 4;
#pragma unroll
    for (int j = 0; j < 4; ++j) {
      if (n + j < N) {
        float s = row[n + j];
        int bi = (int)((s + R) * invW); bi = bi < 0 ? 0 : (bi > NBIN - 1 ? NBIN - 1 : bi);
        if (bi >= hi) { int i = atomicAdd(&cnt[2 * b], 1);     if (i < CAP) cp[i] = packMax(s, n + j); }
        if (bi <= lo) { int i = atomicAdd(&cnt[2 * b + 1], 1); if (i < CAP) cn[i] = packMax(s, n + j) ^ 0xFFFFFFFFull; }
      }
    }
  }
}

// ================= select stage D: exact rank =================
__global__ void __launch_bounds__(256)
rank_kernel(const int* __restrict__ cnt, const u64* __restrict__ candP,
            const u64* __restrict__ candN, int* __restrict__ out, int B, int K) {
  int tid = threadIdx.x, b = blockIdx.x;
  int tP = cnt[2 * b];     tP = tP < CAP ? tP : CAP;
  int tN = cnt[2 * b + 1]; tN = tN < CAP ? tN : CAP;
  const u64* cp = candP + (size_t)b * CAP;
  const u64* cn = candN + (size_t)b * CAP;
  int* pos = out + (size_t)b * K;
  int* neg = out + (size_t)B * K + (size_t)b * K;
  for (int i = tid; i < tP; i += 256) {
    u64 key = cp[i]; int r = 0;
    for (int j = 0; j < tP; ++j) r += (cp[j] > key);
    if (r < K) pos[r] = (int)(~(unsigned)key);
  }
  for (int i = tid; i < tN; i += 256) {
    u64 key = cn[i]; int r = 0;
    for (int j = 0; j < tN; ++j) r += (cn[j] < key);
    if (r < K) neg[r] = (int)(unsigned)key;
  }
}

extern "C" void kernel_launch(void* const* d_in, const int* in_sizes, int n_in,
                              void* d_out, int out_size, void* d_ws, size_t ws_size,
                              hipStream_t stream) {
  const float* basket = (const float*)d_in[0];
  const float* item   = (const float*)d_in[1];
  const float* Wb     = (const float*)d_in[2];
  const float* Wi     = (const float*)d_in[3];
  const float* v      = (const float*)d_in[4];
  int D = in_sizes[4];           // 64
  int B = in_sizes[0] / D;       // 128
  int N = in_sizes[1] / D;       // 50000
  int K = out_size / (2 * B);    // 50

  float* scores = (float*)d_ws;                         // B*N floats = 25.6 MB
  float* ipE    = scores + (size_t)B * N;               // N*64 floats = 12.8 MB
  float* bpE    = ipE + (size_t)N * 64;                 // B*64 floats = 32 KB
  // select structures OVERLAY ipE (dead after scores_kernel)
  int* hist = (int*)ipE;                                // B*NBIN ints = 2 MB
  int* cnt  = hist + (size_t)B * NBIN;                  // 2*B
  int* thr  = cnt + 2 * B;                              // 2*B
  u64* candP = (u64*)(thr + 2 * B);                     // B*CAP u64
  u64* candN = candP + (size_t)B * CAP;

  int nItemBlk = (N + PB - 1) / PB;
  prep_kernel<<<dim3(nItemBlk + 4), dim3(PB), 0, stream>>>(basket, item, Wb, Wi, ipE, bpE, N, B, nItemBlk);

  dim3 gs((N + 255) / 256, (B + BT - 1) / BT);
  scores_kernel<<<gs, dim3(256), 0, stream>>>(ipE, bpE, v, scores, N, B);

  // CH: per-chunk elements, multiple of 1024, ~N/8
  int CH = (((N + 7) / 8) + 1023) & ~1023;
  int nCh = (N + CH - 1) / CH;
  hipMemsetAsync(hist, 0, ((size_t)B * NBIN + 2 * B) * sizeof(int), stream);
  hist_kernel<<<dim3(nCh, B), dim3(256), 0, stream>>>(scores, v, hist, N, CH);
  thr_kernel<<<dim3(B), dim3(64), 0, stream>>>(hist, thr, K);
  compact_kernel<<<dim3(nCh, B), dim3(256), 0, stream>>>(scores, v, thr, cnt, candP, candN, N, CH);
  rank_kernel<<<dim3(B), dim3(256), 0, stream>>>(cnt, candP, candN, (int*)d_out, B, K);
}

// Round 4
// 136.790 us; speedup vs baseline: 2.8543x; 1.0904x over previous
//
#include <hip/hip_runtime.h>

typedef unsigned long long u64;

#define CSC 2.8853900817779268f   // 2*log2(e): tanh(x) = 1 - 2/(exp2(x*CSC)+1)
#define NBIN 4096
#define CAP  256
#define BT   16
#define PB   128
#define MAXJ 16                   // select supports N <= 16*4096

// ---------- sortable key packing ----------
__device__ __forceinline__ unsigned ord32(float f) {
  unsigned u = __float_as_uint(f);
  return (u & 0x80000000u) ? ~u : (u | 0x80000000u);
}
// max-key: descending score, ties -> ascending index (jax.lax.top_k semantics)
__device__ __forceinline__ u64 packMax(float f, int n) {
  return ((u64)ord32(f) << 32) | (unsigned)(~(unsigned)n);
}

// ================= prep: E = exp2(CSC * proj) =================
// ipE [N][64] row-major; bpET [64][B] TRANSPOSED (consecutive baskets per d)
__global__ void __launch_bounds__(128)
prep_kernel(const float* __restrict__ basket, const float* __restrict__ item,
            const float* __restrict__ Wb, const float* __restrict__ Wi,
            float* __restrict__ ipE, float* __restrict__ bpET,
            int N, int B, int nItemBlk) {
  __shared__ float WL[4096];
  int tid = threadIdx.x;

  if (blockIdx.x >= nItemBlk) {                // 4 basket blocks
    for (int i = tid; i < 4096; i += PB) WL[i] = Wb[i];
    __syncthreads();
    int which = blockIdx.x - nItemBlk;
    int seg = (B * 64 + 3) / 4;
    int lo = which * seg, hi = min(lo + seg, B * 64);
    for (int idx = lo + tid; idx < hi; idx += PB) {
      int b = idx >> 6, d = idx & 63;
      float acc = 0.f;
#pragma unroll
      for (int e = 0; e < 64; ++e) acc = fmaf(basket[b * 64 + e], WL[d * 64 + e], acc);
      bpET[(size_t)d * B + b] = __builtin_amdgcn_exp2f(acc * CSC);
    }
    return;
  }

  for (int i = tid; i < 4096; i += PB) WL[i] = Wi[i];
  __syncthreads();
  int n = blockIdx.x * PB + tid;
  if (n >= N) return;

  float row[64];
  const float4* p = (const float4*)(item + (size_t)n * 64);
#pragma unroll
  for (int i = 0; i < 16; ++i) {
    float4 t = p[i];
    row[4 * i] = t.x; row[4 * i + 1] = t.y; row[4 * i + 2] = t.z; row[4 * i + 3] = t.w;
  }
  float4* op = (float4*)(ipE + (size_t)n * 64);
#pragma unroll
  for (int q = 0; q < 16; ++q) {
    float4 o;
    float a0 = 0.f, a1 = 0.f, a2 = 0.f, a3 = 0.f;
#pragma unroll
    for (int e = 0; e < 64; ++e) {
      float re = row[e];
      a0 = fmaf(re, WL[(4 * q + 0) * 64 + e], a0);
      a1 = fmaf(re, WL[(4 * q + 1) * 64 + e], a1);
      a2 = fmaf(re, WL[(4 * q + 2) * 64 + e], a2);
      a3 = fmaf(re, WL[(4 * q + 3) * 64 + e], a3);
    }
    o.x = __builtin_amdgcn_exp2f(a0 * CSC);
    o.y = __builtin_amdgcn_exp2f(a1 * CSC);
    o.z = __builtin_amdgcn_exp2f(a2 * CSC);
    o.w = __builtin_amdgcn_exp2f(a3 * CSC);
    op[q] = o;
  }
}

// ================= scores: d-outer, b-inner (sequential s_loads) =================
__global__ void __launch_bounds__(256, 3)
scores_kernel(const float* __restrict__ ipE, const float* __restrict__ bpET,
              const float* __restrict__ v, float* __restrict__ scores, int N, int B) {
  int tid = threadIdx.x;
  int b0 = blockIdx.y * BT;
  if (b0 > B - BT) b0 = B - BT;              // duplicate-safe clamp
  int n = blockIdx.x * 256 + tid;
  if (n >= N) return;

  float ei[64];
  const float4* p = (const float4*)(ipE + (size_t)n * 64);
#pragma unroll
  for (int i = 0; i < 16; ++i) {
    float4 t = p[i];
    ei[4 * i] = t.x; ei[4 * i + 1] = t.y; ei[4 * i + 2] = t.z; ei[4 * i + 3] = t.w;
  }

  double sv = 0.0;
#pragma unroll
  for (int d = 0; d < 64; ++d) sv += (double)v[d];   // uniform -> s_load

  double acc[BT];
#pragma unroll
  for (int b = 0; b < BT; ++b) acc[b] = 0.0;

#pragma unroll
  for (int g = 0; g < 8; ++g) {
    float gs[BT];
#pragma unroll
    for (int j = 0; j < 8; ++j) {
      int d = g * 8 + j;
      float vd = v[d];                               // sgpr, fixed over b
      float eid = ei[d];                             // vgpr, fixed over b
      const float* er = bpET + (size_t)d * B + b0;   // 16 consecutive -> s_load_dwordx8
#pragma unroll
      for (int b = 0; b < BT; ++b) {
        float u1 = fmaf(er[b], eid, 1.0f);           // exp2(b+i)+1 via product
        float r  = __builtin_amdgcn_rcpf(u1);
        gs[b] = (j == 0) ? vd * r : fmaf(vd, r, gs[b]);
      }
    }
#pragma unroll
    for (int b = 0; b < BT; ++b) acc[b] += (double)gs[b];   // f64 fold every 8 d
  }

  size_t base = (size_t)b0 * N + n;
#pragma unroll
  for (int b = 0; b < BT; ++b)
    scores[base + (size_t)b * N] = (float)(sv - 2.0 * acc[b]);
}

// ================= select: whole pipeline in ONE kernel (1 block = 1 row) =================
__global__ void __launch_bounds__(1024)
select_kernel(const float* __restrict__ scores, const float* __restrict__ v,
              int* __restrict__ out, int N, int B, int K) {
  __shared__ int lh[NBIN];
  __shared__ int part[64];
  __shared__ u64 candP[CAP], candN[CAP];
  __shared__ int cntP, cntN, hHi, hLo;
  int tid = threadIdx.x, b = blockIdx.x;
  const float* row = scores + (size_t)b * N;

  for (int i = tid; i < NBIN; i += 1024) lh[i] = 0;
  if (tid == 0) { cntP = 0; cntN = 0; }

  // |score| < R = sum|v_d| strictly (|tanh|<1) -> linear bins over [-R, R]
  float R = 0.f;
#pragma unroll
  for (int d = 0; d < 64; ++d) R += fabsf(v[d]);     // uniform
  float invW = (float)NBIN / (2.f * R);
  __syncthreads();

  // pass 1: load into REGISTERS + histogram
  float4 v4[MAXJ];
#pragma unroll
  for (int j = 0; j < MAXJ; ++j) {
    int f4 = j * 1024 + tid;
    if (j * 4096 < N && f4 * 4 < N) {
      float4 s4 = *(const float4*)(row + (size_t)f4 * 4);
      v4[j] = s4;
      int n0 = f4 * 4;
      float ss[4] = {s4.x, s4.y, s4.z, s4.w};
#pragma unroll
      for (int c = 0; c < 4; ++c) {
        if (n0 + c < N) {
          int bi = (int)((ss[c] + R) * invW);
          bi = bi < 0 ? 0 : (bi > NBIN - 1 ? NBIN - 1 : bi);
          atomicAdd(&lh[bi], 1);
        }
      }
    }
  }
  __syncthreads();

  if (tid < 64) {                  // 64-bin chunk sums
    int s = 0;
    for (int jj = 0; jj < 64; ++jj) s += lh[tid * 64 + jj];
    part[tid] = s;
  }
  __syncthreads();
  if (tid == 0) {                  // top threshold bin
    int cum = 0, c = 63;
    for (; c > 0; --c) { if (cum + part[c] >= K) break; cum += part[c]; }
    int hh = c * 64 + 63;
    for (;; --hh) { cum += lh[hh]; if (cum >= K || hh == 0) break; }
    hHi = hh;
  }
  if (tid == 1) {                  // bottom threshold bin
    int cum = 0, c = 0;
    for (; c < 63; ++c) { if (cum + part[c] >= K) break; cum += part[c]; }
    int hl = c * 64;
    for (;; ++hl) { cum += lh[hl]; if (cum >= K || hl == NBIN - 1) break; }
    hLo = hl;
  }
  __syncthreads();
  int hi = hHi, lo = hLo;

  // pass 2: compact from registers (no memory re-read)
#pragma unroll
  for (int j = 0; j < MAXJ; ++j) {
    int f4 = j * 1024 + tid;
    if (j * 4096 < N && f4 * 4 < N) {
      int n0 = f4 * 4;
      float ss[4] = {v4[j].x, v4[j].y, v4[j].z, v4[j].w};
#pragma unroll
      for (int c = 0; c < 4; ++c) {
        if (n0 + c < N) {
          float s = ss[c];
          int bi = (int)((s + R) * invW);
          bi = bi < 0 ? 0 : (bi > NBIN - 1 ? NBIN - 1 : bi);
          if (bi >= hi) { int i = atomicAdd(&cntP, 1); if (i < CAP) candP[i] = packMax(s, n0 + c); }
          if (bi <= lo) { int i = atomicAdd(&cntN, 1); if (i < CAP) candN[i] = packMax(s, n0 + c) ^ 0xFFFFFFFFull; }
        }
      }
    }
  }
  __syncthreads();

  // exact rank, O(C^2); keys unique -> ranks unique & complete
  int tP = cntP < CAP ? cntP : CAP;
  int tN = cntN < CAP ? cntN : CAP;
  int* pos = out + (size_t)b * K;
  int* neg = out + (size_t)B * K + (size_t)b * K;
  for (int i = tid; i < tP; i += 1024) {
    u64 key = candP[i]; int r = 0;
    for (int jj = 0; jj < tP; ++jj) r += (candP[jj] > key);
    if (r < K) pos[r] = (int)(~(unsigned)key);
  }
  for (int i = tid; i < tN; i += 1024) {
    u64 key = candN[i]; int r = 0;
    for (int jj = 0; jj < tN; ++jj) r += (candN[jj] < key);
    if (r < K) neg[r] = (int)(unsigned)key;
  }
}

extern "C" void kernel_launch(void* const* d_in, const int* in_sizes, int n_in,
                              void* d_out, int out_size, void* d_ws, size_t ws_size,
                              hipStream_t stream) {
  const float* basket = (const float*)d_in[0];
  const float* item   = (const float*)d_in[1];
  const float* Wb     = (const float*)d_in[2];
  const float* Wi     = (const float*)d_in[3];
  const float* v      = (const float*)d_in[4];
  int D = in_sizes[4];           // 64
  int B = in_sizes[0] / D;       // 128
  int N = in_sizes[1] / D;       // 50000
  int K = out_size / (2 * B);    // 50

  float* scores = (float*)d_ws;                         // B*N floats = 25.6 MB
  float* ipE    = scores + (size_t)B * N;               // N*64 floats = 12.8 MB
  float* bpET   = ipE + (size_t)N * 64;                 // 64*B floats = 32 KB

  int nItemBlk = (N + PB - 1) / PB;
  prep_kernel<<<dim3(nItemBlk + 4), dim3(PB), 0, stream>>>(basket, item, Wb, Wi, ipE, bpET, N, B, nItemBlk);

  dim3 gs((N + 255) / 256, (B + BT - 1) / BT);
  scores_kernel<<<gs, dim3(256), 0, stream>>>(ipE, bpET, v, scores, N, B);

  select_kernel<<<dim3(B), dim3(1024), 0, stream>>>(scores, v, (int*)d_out, N, B, K);
}